// Round 1
// baseline (25.000 us; speedup 1.0000x reference)
//
#include <hip/hip_runtime.h>
#include <math.h>

// Fused HybridQuadTTN: patchify + linear/tanh + 3 rounds of regroup+4-qubit
// circuit + head, one wave (64 lanes) per batch element.
//
// Circuit algebra (per row, angles a0..a3, stage weights W[2][4][3]):
//   |psi> = RX(a_w) on each wire -> product state
//   layer0: Rot gates + CNOT ring r=1
//   layer1: Rot gates + CNOT ring r=2, measure <Z0>
// Reduction: Z0 conjugated through ring r=2 == Z2; Rot-layer1 on wires!=2
// cancels; so  e = <phi| M_2 |phi>,  M = Rot1_2^dag Z Rot1_2,  phi = state
// after layer-0 ring.  Layer-0 Rot fused into the per-wire init 2-vectors.

__device__ __forceinline__ void make_gate(const float* __restrict__ wv, float* g) {
  // PennyLane Rot(phi, theta, omega) = RZ(omega) RY(theta) RZ(phi)
  float ct, st, cp, sp, cm, sm;
  sincosf(0.5f * wv[1], &st, &ct);
  sincosf(0.5f * (wv[0] + wv[2]), &sp, &cp);
  sincosf(0.5f * (wv[0] - wv[2]), &sm, &cm);
  g[0] =  cp * ct; g[1] = -sp * ct;   // g00
  g[2] = -cm * st; g[3] = -sm * st;   // g01
  g[4] =  cm * st; g[5] = -sm * st;   // g10
  g[6] =  cp * ct; g[7] =  sp * ct;   // g11
}

// SG: 36 floats in LDS: 4 layer-0 Rot gates (8 floats each) + M (M00,M11,M01r,M01i)
__device__ __forceinline__ float run_circuit(float a0, float a1, float a2, float a3,
                                             const float* __restrict__ SG) {
  float cw[4], sw[4];
  __sincosf(0.5f * a0, &sw[0], &cw[0]);
  __sincosf(0.5f * a1, &sw[1], &cw[1]);
  __sincosf(0.5f * a2, &sw[2], &cw[2]);
  __sincosf(0.5f * a3, &sw[3], &cw[3]);

  // v_w = Rot0_w * (c, -i s)^T   (first column of Rot0_w * RX applied to |0>)
  float vr[4][2], vi[4][2];
#pragma unroll
  for (int w = 0; w < 4; ++w) {
    const float* g = SG + w * 8;
    float c = cw[w], s = sw[w];
    vr[w][0] = g[0] * c + g[3] * s;
    vi[w][0] = g[1] * c - g[2] * s;
    vr[w][1] = g[4] * c + g[7] * s;
    vi[w][1] = g[5] * c - g[6] * s;
  }
  // amp(idx) = v0[b0] v1[b1] v2[b2] v3[b3], wire w <-> bit (3-w)
  float uhr[4], uhi[4], ulr[4], uli[4];
#pragma unroll
  for (int h = 0; h < 4; ++h) {
    int b0 = h >> 1, b1 = h & 1;
    uhr[h] = vr[0][b0] * vr[1][b1] - vi[0][b0] * vi[1][b1];
    uhi[h] = vr[0][b0] * vi[1][b1] + vi[0][b0] * vr[1][b1];
    ulr[h] = vr[2][b0] * vr[3][b1] - vi[2][b0] * vi[3][b1];
    uli[h] = vr[2][b0] * vi[3][b1] + vi[2][b0] * vr[3][b1];
  }
  float sr[16], si[16];
#pragma unroll
  for (int i = 0; i < 16; ++i) {
    int h = i >> 2, l = i & 3;
    sr[i] = uhr[h] * ulr[l] - uhi[h] * uli[l];
    si[i] = uhr[h] * uli[l] + uhi[h] * ulr[l];
  }
  // CNOT ring r=1: (0,1),(1,2),(2,3),(3,0) -- compile-time register swaps
#pragma unroll
  for (int w = 0; w < 4; ++w) {
    int cm = 8 >> w;
    int tm = 8 >> ((w + 1) & 3);
#pragma unroll
    for (int i = 0; i < 16; ++i) {
      if ((i & cm) && !(i & tm)) {
        int j = i | tm;
        float t;
        t = sr[i]; sr[i] = sr[j]; sr[j] = t;
        t = si[i]; si[i] = si[j]; si[j] = t;
      }
    }
  }
  // e = sum over wire-2 pairs of [abar bbar] M [a;b]
  float M00 = SG[32], M11 = SG[33], M01r = SG[34], M01i = SG[35];
  float e = 0.f;
#pragma unroll
  for (int i = 0; i < 16; ++i) {
    if (i & 2) continue;
    int j = i | 2;
    float ar = sr[i], ai = si[i], br = sr[j], bi = si[j];
    e += M00 * (ar * ar + ai * ai) + M11 * (br * br + bi * bi)
       + 2.f * (M01r * (ar * br + ai * bi) - M01i * (ar * bi - ai * br));
  }
  return e;
}

__global__ __launch_bounds__(256) void fused_ttn(
    const float* __restrict__ x, const float* __restrict__ We,
    const float* __restrict__ be, const float* __restrict__ w1,
    const float* __restrict__ w2, const float* __restrict__ w3,
    const float* __restrict__ Wh, const float* __restrict__ bh,
    float* __restrict__ out, int B) {
  __shared__ float sG[3 * 36];
  __shared__ float sWe[64];
  __shared__ float sbe[4];
  __shared__ float sWh[10];
  __shared__ float sbh[10];
  __shared__ float qbuf[4][64];
  __shared__ float q2buf[4][16];
  __shared__ float e3buf[4][4];

  int tid = threadIdx.x;
  if (tid < 12) {
    int s = tid >> 2, w = tid & 3;
    const float* W = (s == 0) ? w1 : (s == 1) ? w2 : w3;
    make_gate(W + w * 3, &sG[s * 36 + w * 8]);           // layer-0 gates
  } else if (tid < 15) {
    int s = tid - 12;
    const float* W = (s == 0) ? w1 : (s == 1) ? w2 : w3;
    float g[8];
    make_gate(W + 18, g);                                // layer-1, wire 2
    float* m = &sG[s * 36 + 32];                         // M = g^dag Z g
    m[0] = g[0]*g[0] + g[1]*g[1] - (g[4]*g[4] + g[5]*g[5]);
    m[1] = g[2]*g[2] + g[3]*g[3] - (g[6]*g[6] + g[7]*g[7]);
    m[2] = g[0]*g[2] + g[1]*g[3] - (g[4]*g[6] + g[5]*g[7]);
    m[3] = g[0]*g[3] - g[1]*g[2] - (g[4]*g[7] - g[5]*g[6]);
  }
  if (tid < 64) sWe[tid] = We[tid];
  if (tid < 4)  sbe[tid] = be[tid];
  if (tid < 10) { sWh[tid] = Wh[tid]; sbh[tid] = bh[tid]; }
  __syncthreads();

  int wv = tid >> 6, lane = tid & 63;
  int b = blockIdx.x * 4 + wv;
  bool valid = (b < B);
  int bb = valid ? b : 0;

  // ---- patch embed: lane = patch (ph, pw); feature (p1,p2) = x[ph*4+p1, pw*4+p2]
  int ph = lane >> 3, pw = lane & 7;
  const float4* xb = (const float4*)(x + (size_t)bb * 1024);
  float acc[4] = {sbe[0], sbe[1], sbe[2], sbe[3]};
#pragma unroll
  for (int p1 = 0; p1 < 4; ++p1) {
    float4 v = xb[(ph * 4 + p1) * 8 + pw];
    float vv[4] = {v.x, v.y, v.z, v.w};
#pragma unroll
    for (int p2 = 0; p2 < 4; ++p2) {
      int f = p1 * 4 + p2;
#pragma unroll
      for (int j = 0; j < 4; ++j) acc[j] += vv[p2] * sWe[f * 4 + j];
    }
  }

  // ---- stage 1: one circuit per patch; angles = h1[p][0..3]
  float e1 = run_circuit(tanhf(acc[0]), tanhf(acc[1]), tanhf(acc[2]), tanhf(acc[3]),
                         &sG[0]);
  // regroup(h=8) row order: q1[g*4+r], g=(ph>>1)*4+(pw>>1), r=(ph&1)*2+(pw&1)
  int grp = (ph >> 1) * 4 + (pw >> 1);
  int sub = (ph & 1) * 2 + (pw & 1);
  qbuf[wv][grp * 4 + sub] = e1;
  __syncthreads();

  // ---- stage 2: 16 circuits; regroup(h=4): angles f=(a2,a4) at a1*32+a2*16+a3*2+a4
  if (lane < 16) {
    int a1 = lane >> 3, a3 = lane & 7;
    int base = a1 * 32 + a3 * 2;
    float e2 = run_circuit(qbuf[wv][base], qbuf[wv][base + 1],
                           qbuf[wv][base + 16], qbuf[wv][base + 17], &sG[36]);
    q2buf[wv][lane] = e2;
  }
  __syncthreads();

  // ---- stage 3: 4 circuits; regroup(h=2): angles f=(d1,d3) at d1*8+g3*2+d3
  if (lane < 4) {
    int base = lane * 2;
    float e3 = run_circuit(q2buf[wv][base], q2buf[wv][base + 1],
                           q2buf[wv][base + 8], q2buf[wv][base + 9], &sG[72]);
    e3buf[wv][lane] = e3;
  }
  __syncthreads();

  // ---- head: out[b, g3, k] = e3[g3]*Wh[k] + bh[k]
  if (valid && lane < 40) {
    int g3 = lane / 10;
    int k = lane - g3 * 10;
    out[(size_t)b * 40 + lane] = e3buf[wv][g3] * sWh[k] + sbh[k];
  }
}

extern "C" void kernel_launch(void* const* d_in, const int* in_sizes, int n_in,
                              void* d_out, int out_size, void* d_ws, size_t ws_size,
                              hipStream_t stream) {
  const float* x  = (const float*)d_in[0];
  const float* We = (const float*)d_in[1];
  const float* be = (const float*)d_in[2];
  const float* w1 = (const float*)d_in[3];
  const float* w2 = (const float*)d_in[4];
  const float* w3 = (const float*)d_in[5];
  const float* Wh = (const float*)d_in[6];
  const float* bh = (const float*)d_in[7];
  float* out = (float*)d_out;

  int B = in_sizes[0] / 1024;           // x is (B, 1, 32, 32)
  int blocks = (B + 3) / 4;             // 4 batch elements (waves) per block
  hipLaunchKernelGGL(fused_ttn, dim3(blocks), dim3(256), 0, stream,
                     x, We, be, w1, w2, w3, Wh, bh, out, B);
}

// Round 2
// 12.618 us; speedup vs baseline: 1.9813x; 1.9813x over previous
//
#include <hip/hip_runtime.h>
#include <math.h>

#define NELEM 16  // batch elements per 256-thread block

// Rot(phi, theta, omega) = RZ(omega) RY(theta) RZ(phi), 2x2 complex
__device__ __forceinline__ void make_gate(float phi, float th, float om, float* g) {
  float ct, st, cp, sp, cm, sm;
  __sincosf(0.5f * th, &st, &ct);
  __sincosf(0.5f * (phi + om), &sp, &cp);
  __sincosf(0.5f * (phi - om), &sm, &cm);
  g[0] =  cp * ct; g[1] = -sp * ct;   // g00
  g[2] = -cm * st; g[3] = -sm * st;   // g01
  g[4] =  cm * st; g[5] = -sm * st;   // g10
  g[6] =  cp * ct; g[7] =  sp * ct;   // g11
}

__device__ __forceinline__ float fast_tanh(float x) {
  float e = __expf(2.0f * x);
  return __builtin_fmaf(-2.0f, __builtin_amdgcn_rcpf(e + 1.0f), 1.0f);
}

// Whole 4-qubit 2-layer circuit + <Z0> collapsed to sinusoids in the 4 angles:
//   e = A*t0*t1*t2 + k3r*(Br*k2r + Bi*t0*t1*k2i)
// with X = P + Q*cos(a) + R*sin(a) per wire (P=0 for the t's).
// K layout: [0..1] Qt0,Rt0 [2..3] Qt1,Rt1 [4..5] Qt2,Rt2
//           [6..8] P,Q,R of k2r  [9..11] P,Q,R of k2i  [12..14] P,Q,R of k3r
//           [15] A  [16] Br=4*M01r  [17] Bi=-4*M01i
__device__ __forceinline__ float circuit18(float a0, float a1, float a2, float a3,
                                           const float* __restrict__ K) {
  float s0, c0, s1, c1, s2, c2, s3, c3;
  __sincosf(a0, &s0, &c0);
  __sincosf(a1, &s1, &c1);
  __sincosf(a2, &s2, &c2);
  __sincosf(a3, &s3, &c3);
  float t0  = K[0] * c0 + K[1] * s0;
  float t1  = K[2] * c1 + K[3] * s1;
  float t2  = K[4] * c2 + K[5] * s2;
  float k2r = K[6] + K[7] * c2 + K[8] * s2;
  float k2i = K[9] + K[10] * c2 + K[11] * s2;
  float k3r = K[12] + K[13] * c3 + K[14] * s3;
  float tt = t0 * t1;
  return K[15] * (tt * t2) + k3r * (K[16] * k2r + K[17] * (tt * k2i));
}

__global__ __launch_bounds__(256, 2) void fused_ttn(
    const float* __restrict__ x, const float* __restrict__ We,
    const float* __restrict__ be, const float* __restrict__ w1,
    const float* __restrict__ w2, const float* __restrict__ w3,
    const float* __restrict__ Wh, const float* __restrict__ bh,
    float* __restrict__ out, int B) {
  __shared__ __align__(16) float sC[3][20];     // 18 consts per stage
  __shared__ __align__(16) float sWe[64];
  __shared__ float sbe[4];
  __shared__ float sWh[10];
  __shared__ float sbh[10];
  __shared__ float qbuf[NELEM * 65];            // stage-1 outs, padded stride
  __shared__ float q2buf[NELEM * 17];           // stage-2 outs
  __shared__ float e3buf[NELEM * 4];            // stage-3 outs

  const int t = threadIdx.x;
  const int wv = t >> 6, lane = t & 63;
  const int ph = lane >> 3, pw = lane & 7;

  // ---- issue all x loads first (16 float4 per thread = 4 elements' patches)
  float4 xv[16];
  const float4* xb = (const float4*)x;
#pragma unroll
  for (int it = 0; it < 4; ++it) {
    size_t gb = (size_t)blockIdx.x * NELEM + (it * 4 + wv);
    if (gb >= (size_t)B) gb = 0;
#pragma unroll
    for (int p1 = 0; p1 < 4; ++p1)
      xv[it * 4 + p1] = xb[gb * 256 + (ph * 4 + p1) * 8 + pw];
  }

  // ---- per-block constant setup (redundant across blocks, ~trivial)
  if (t < 12) {
    int s = t >> 2, w = t & 3;
    const float* W = (s == 0) ? w1 : (s == 1) ? w2 : w3;
    float g[8];
    make_gate(W[w * 3], W[w * 3 + 1], W[w * 3 + 2], g);
    float* K = &sC[s][0];
    float Qt = g[0] * g[0] + g[1] * g[1] - g[4] * g[4] - g[5] * g[5];
    float Rt = (g[0] * g[3] - g[1] * g[2]) - (g[4] * g[7] - g[5] * g[6]);
    if (w < 2) {
      K[w * 2] = Qt; K[w * 2 + 1] = Rt;
    } else if (w == 2) {
      K[4] = Qt; K[5] = Rt;
      float u  = g[0] * g[4] + g[1] * g[5], v  = g[2] * g[6] + g[3] * g[7];
      float p  = g[0] * g[5] - g[1] * g[4], q  = g[2] * g[7] - g[3] * g[6];
      float r1 = g[2] * g[4] + g[3] * g[5], m1 = g[2] * g[5] - g[3] * g[4];
      float r2 = g[0] * g[6] + g[1] * g[7], m2 = g[0] * g[7] - g[1] * g[6];
      K[6] = 0.5f * (u + v);  K[7]  = 0.5f * (u - v);  K[8]  = 0.5f * (m2 - m1);
      K[9] = 0.5f * (p + q);  K[10] = 0.5f * (p - q);  K[11] = 0.5f * (r1 - r2);
    } else {  // w == 3: k3r consts
      float u  = g[0] * g[4] + g[1] * g[5], v  = g[2] * g[6] + g[3] * g[7];
      float m1 = g[2] * g[5] - g[3] * g[4], m2 = g[0] * g[7] - g[1] * g[6];
      K[12] = 0.5f * (u + v); K[13] = 0.5f * (u - v); K[14] = 0.5f * (m2 - m1);
    }
  } else if (t < 15) {
    int s = t - 12;
    const float* W = (s == 0) ? w1 : (s == 1) ? w2 : w3;
    float g[8];
    make_gate(W[18], W[19], W[20], g);  // layer 1, wire 2
    float A    = g[0] * g[0] + g[1] * g[1] - g[4] * g[4] - g[5] * g[5];
    float M01r = g[0] * g[2] + g[1] * g[3] - (g[4] * g[6] + g[5] * g[7]);
    float M01i = (g[0] * g[3] - g[1] * g[2]) - (g[4] * g[7] - g[5] * g[6]);
    sC[s][15] = A; sC[s][16] = 4.0f * M01r; sC[s][17] = -4.0f * M01i;
  }
  if (t < 64) sWe[t] = We[t];
  if (t < 4)  sbe[t] = be[t];
  if (t < 10) { sWh[t] = Wh[t]; sbh[t] = bh[t]; }
  __syncthreads();

  // ---- stage 1: 4 passes, one circuit per thread per pass
  const int grp = (ph >> 1) * 4 + (pw >> 1);
  const int sub = (ph & 1) * 2 + (pw & 1);
  float be0 = sbe[0], be1 = sbe[1], be2 = sbe[2], be3 = sbe[3];
#pragma unroll
  for (int it = 0; it < 4; ++it) {
    float a0 = be0, a1 = be1, a2 = be2, a3 = be3;
#pragma unroll
    for (int p1 = 0; p1 < 4; ++p1) {
      float4 v = xv[it * 4 + p1];
      float vv[4] = {v.x, v.y, v.z, v.w};
#pragma unroll
      for (int p2 = 0; p2 < 4; ++p2) {
        int f = p1 * 4 + p2;
        a0 = __builtin_fmaf(vv[p2], sWe[f * 4 + 0], a0);
        a1 = __builtin_fmaf(vv[p2], sWe[f * 4 + 1], a1);
        a2 = __builtin_fmaf(vv[p2], sWe[f * 4 + 2], a2);
        a3 = __builtin_fmaf(vv[p2], sWe[f * 4 + 3], a3);
      }
    }
    float e1 = circuit18(fast_tanh(a0), fast_tanh(a1), fast_tanh(a2),
                         fast_tanh(a3), &sC[0][0]);
    qbuf[(it * 4 + wv) * 65 + grp * 4 + sub] = e1;
  }
  __syncthreads();

  // ---- stage 2: 256 circuits (16 elem x 16), full block
  {
    int e2 = t >> 4, c = t & 15;
    int base = e2 * 65 + (c >> 3) * 32 + (c & 7) * 2;
    float r = circuit18(qbuf[base], qbuf[base + 1], qbuf[base + 16],
                        qbuf[base + 17], &sC[1][0]);
    q2buf[e2 * 17 + c] = r;
  }
  __syncthreads();

  // ---- stage 3: 64 circuits (16 elem x 4), one wave
  if (t < 64) {
    int e3 = t >> 2, c = t & 3;
    int base = e3 * 17 + c * 2;
    float r = circuit18(q2buf[base], q2buf[base + 1], q2buf[base + 8],
                        q2buf[base + 9], &sC[2][0]);
    e3buf[e3 * 4 + c] = r;
  }
  __syncthreads();

  // ---- head: 640 outputs per block
  size_t ob = (size_t)blockIdx.x * (NELEM * 40);
#pragma unroll
  for (int rpt = 0; rpt < 3; ++rpt) {
    int o = t + rpt * 256;
    if (o < NELEM * 40) {
      int eo = o / 40;
      int j  = o - eo * 40;
      int g3 = j / 10;
      int k  = j - g3 * 10;
      int b  = blockIdx.x * NELEM + eo;
      if (b < B) out[ob + o] = e3buf[eo * 4 + g3] * sWh[k] + sbh[k];
    }
  }
}

extern "C" void kernel_launch(void* const* d_in, const int* in_sizes, int n_in,
                              void* d_out, int out_size, void* d_ws, size_t ws_size,
                              hipStream_t stream) {
  (void)n_in; (void)out_size; (void)d_ws; (void)ws_size;
  const float* x  = (const float*)d_in[0];
  const float* We = (const float*)d_in[1];
  const float* be = (const float*)d_in[2];
  const float* w1 = (const float*)d_in[3];
  const float* w2 = (const float*)d_in[4];
  const float* w3 = (const float*)d_in[5];
  const float* Wh = (const float*)d_in[6];
  const float* bh = (const float*)d_in[7];
  float* out = (float*)d_out;

  int B = in_sizes[0] / 1024;  // x is (B, 1, 32, 32)
  int blocks = (B + NELEM - 1) / NELEM;
  hipLaunchKernelGGL(fused_ttn, dim3(blocks), dim3(256), 0, stream,
                     x, We, be, w1, w2, w3, Wh, bh, out, B);
}

// Round 3
// 11.664 us; speedup vs baseline: 2.1435x; 1.0818x over previous
//
#include <hip/hip_runtime.h>
#include <math.h>

#define NELEM 4  // batch elements per 256-thread block (one per wave)

// Rot(phi, theta, omega) = RZ(omega) RY(theta) RZ(phi), 2x2 complex
__device__ __forceinline__ void make_gate(float phi, float th, float om, float* g) {
  float ct, st, cp, sp, cm, sm;
  __sincosf(0.5f * th, &st, &ct);
  __sincosf(0.5f * (phi + om), &sp, &cp);
  __sincosf(0.5f * (phi - om), &sm, &cm);
  g[0] =  cp * ct; g[1] = -sp * ct;   // g00
  g[2] = -cm * st; g[3] = -sm * st;   // g01
  g[4] =  cm * st; g[5] = -sm * st;   // g10
  g[6] =  cp * ct; g[7] =  sp * ct;   // g11
}

__device__ __forceinline__ float fast_tanh(float x) {
  float e = __expf(2.0f * x);
  return __builtin_fmaf(-2.0f, __builtin_amdgcn_rcpf(e + 1.0f), 1.0f);
}

// Whole 4-qubit 2-layer circuit + <Z0> collapsed to sinusoids in the 4 angles:
//   e = A*t0*t1*t2 + k3r*(Br*k2r + Bi*t0*t1*k2i)
// with X = P + Q*cos(a) + R*sin(a) per wire (P=0 for the t's).
__device__ __forceinline__ float circuit18(float a0, float a1, float a2, float a3,
                                           const float* __restrict__ K) {
  float s0, c0, s1, c1, s2, c2, s3, c3;
  __sincosf(a0, &s0, &c0);
  __sincosf(a1, &s1, &c1);
  __sincosf(a2, &s2, &c2);
  __sincosf(a3, &s3, &c3);
  float t0  = K[0] * c0 + K[1] * s0;
  float t1  = K[2] * c1 + K[3] * s1;
  float t2  = K[4] * c2 + K[5] * s2;
  float k2r = K[6] + K[7] * c2 + K[8] * s2;
  float k2i = K[9] + K[10] * c2 + K[11] * s2;
  float k3r = K[12] + K[13] * c3 + K[14] * s3;
  float tt = t0 * t1;
  return K[15] * (tt * t2) + k3r * (K[16] * k2r + K[17] * (tt * k2i));
}

__global__ __launch_bounds__(256, 4) void fused_ttn(
    const float* __restrict__ x, const float* __restrict__ We,
    const float* __restrict__ be, const float* __restrict__ w1,
    const float* __restrict__ w2, const float* __restrict__ w3,
    const float* __restrict__ Wh, const float* __restrict__ bh,
    float* __restrict__ out, int B) {
  __shared__ __align__(16) float sC[3][20];     // 18 consts per stage
  __shared__ __align__(16) float sWe[64];
  __shared__ float sbe[4];
  __shared__ float sWh[10];
  __shared__ float sbh[10];
  __shared__ float qbuf[NELEM * 65];            // stage-1 outs, padded stride
  __shared__ float q2buf[NELEM * 17];           // stage-2 outs
  __shared__ float e3buf[NELEM * 4];            // stage-3 outs

  const int t = threadIdx.x;
  const int wv = t >> 6, lane = t & 63;
  const int ph = lane >> 3, pw = lane & 7;

  // ---- issue all x loads first (4 float4 per thread = this wave's element)
  float4 xv[4];
  const float4* xb = (const float4*)x;
  size_t gb = (size_t)blockIdx.x * NELEM + wv;
  if (gb >= (size_t)B) gb = 0;
#pragma unroll
  for (int p1 = 0; p1 < 4; ++p1)
    xv[p1] = xb[gb * 256 + (ph * 4 + p1) * 8 + pw];

  // ---- per-block constant setup (redundant across blocks, ~trivial)
  if (t < 12) {
    int s = t >> 2, w = t & 3;
    const float* W = (s == 0) ? w1 : (s == 1) ? w2 : w3;
    float g[8];
    make_gate(W[w * 3], W[w * 3 + 1], W[w * 3 + 2], g);
    float* K = &sC[s][0];
    float Qt = g[0] * g[0] + g[1] * g[1] - g[4] * g[4] - g[5] * g[5];
    float Rt = (g[0] * g[3] - g[1] * g[2]) - (g[4] * g[7] - g[5] * g[6]);
    if (w < 2) {
      K[w * 2] = Qt; K[w * 2 + 1] = Rt;
    } else if (w == 2) {
      K[4] = Qt; K[5] = Rt;
      float u  = g[0] * g[4] + g[1] * g[5], v  = g[2] * g[6] + g[3] * g[7];
      float p  = g[0] * g[5] - g[1] * g[4], q  = g[2] * g[7] - g[3] * g[6];
      float r1 = g[2] * g[4] + g[3] * g[5], m1 = g[2] * g[5] - g[3] * g[4];
      float r2 = g[0] * g[6] + g[1] * g[7], m2 = g[0] * g[7] - g[1] * g[6];
      K[6] = 0.5f * (u + v);  K[7]  = 0.5f * (u - v);  K[8]  = 0.5f * (m2 - m1);
      K[9] = 0.5f * (p + q);  K[10] = 0.5f * (p - q);  K[11] = 0.5f * (r1 - r2);
    } else {  // w == 3: k3r consts
      float u  = g[0] * g[4] + g[1] * g[5], v  = g[2] * g[6] + g[3] * g[7];
      float m1 = g[2] * g[5] - g[3] * g[4], m2 = g[0] * g[7] - g[1] * g[6];
      K[12] = 0.5f * (u + v); K[13] = 0.5f * (u - v); K[14] = 0.5f * (m2 - m1);
    }
  } else if (t < 15) {
    int s = t - 12;
    const float* W = (s == 0) ? w1 : (s == 1) ? w2 : w3;
    float g[8];
    make_gate(W[18], W[19], W[20], g);  // layer 1, wire 2
    float A    = g[0] * g[0] + g[1] * g[1] - g[4] * g[4] - g[5] * g[5];
    float M01r = g[0] * g[2] + g[1] * g[3] - (g[4] * g[6] + g[5] * g[7]);
    float M01i = (g[0] * g[3] - g[1] * g[2]) - (g[4] * g[7] - g[5] * g[6]);
    sC[s][15] = A; sC[s][16] = 4.0f * M01r; sC[s][17] = -4.0f * M01i;
  }
  if (t < 64) sWe[t] = We[t];
  if (t < 4)  sbe[t] = be[t];
  if (t < 10) { sWh[t] = Wh[t]; sbh[t] = bh[t]; }
  __syncthreads();

  // ---- stage 1: one circuit per thread (lane = patch, wave = element)
  const int grp = (ph >> 1) * 4 + (pw >> 1);
  const int sub = (ph & 1) * 2 + (pw & 1);
  float a0 = sbe[0], a1 = sbe[1], a2 = sbe[2], a3 = sbe[3];
#pragma unroll
  for (int p1 = 0; p1 < 4; ++p1) {
    float4 v = xv[p1];
    float vv[4] = {v.x, v.y, v.z, v.w};
#pragma unroll
    for (int p2 = 0; p2 < 4; ++p2) {
      int f = p1 * 4 + p2;
      a0 = __builtin_fmaf(vv[p2], sWe[f * 4 + 0], a0);
      a1 = __builtin_fmaf(vv[p2], sWe[f * 4 + 1], a1);
      a2 = __builtin_fmaf(vv[p2], sWe[f * 4 + 2], a2);
      a3 = __builtin_fmaf(vv[p2], sWe[f * 4 + 3], a3);
    }
  }
  float e1 = circuit18(fast_tanh(a0), fast_tanh(a1), fast_tanh(a2),
                       fast_tanh(a3), &sC[0][0]);
  qbuf[wv * 65 + grp * 4 + sub] = e1;
  __syncthreads();

  // ---- stage 2: 64 circuits (4 elem x 16)
  if (t < NELEM * 16) {
    int e2 = t >> 4, c = t & 15;
    int base = e2 * 65 + (c >> 3) * 32 + (c & 7) * 2;
    float r = circuit18(qbuf[base], qbuf[base + 1], qbuf[base + 16],
                        qbuf[base + 17], &sC[1][0]);
    q2buf[e2 * 17 + c] = r;
  }
  __syncthreads();

  // ---- stage 3: 16 circuits (4 elem x 4)
  if (t < NELEM * 4) {
    int e3 = t >> 2, c = t & 3;
    int base = e3 * 17 + c * 2;
    float r = circuit18(q2buf[base], q2buf[base + 1], q2buf[base + 8],
                        q2buf[base + 9], &sC[2][0]);
    e3buf[e3 * 4 + c] = r;
  }
  __syncthreads();

  // ---- head: 160 outputs per block
  if (t < NELEM * 40) {
    int eo = t / 40;
    int j  = t - eo * 40;
    int g3 = j / 10;
    int k  = j - g3 * 10;
    int b  = blockIdx.x * NELEM + eo;
    if (b < B) out[(size_t)blockIdx.x * (NELEM * 40) + t] =
        e3buf[eo * 4 + g3] * sWh[k] + sbh[k];
  }
}

extern "C" void kernel_launch(void* const* d_in, const int* in_sizes, int n_in,
                              void* d_out, int out_size, void* d_ws, size_t ws_size,
                              hipStream_t stream) {
  (void)n_in; (void)out_size; (void)d_ws; (void)ws_size;
  const float* x  = (const float*)d_in[0];
  const float* We = (const float*)d_in[1];
  const float* be = (const float*)d_in[2];
  const float* w1 = (const float*)d_in[3];
  const float* w2 = (const float*)d_in[4];
  const float* w3 = (const float*)d_in[5];
  const float* Wh = (const float*)d_in[6];
  const float* bh = (const float*)d_in[7];
  float* out = (float*)d_out;

  int B = in_sizes[0] / 1024;  // x is (B, 1, 32, 32)
  int blocks = (B + NELEM - 1) / NELEM;
  hipLaunchKernelGGL(fused_ttn, dim3(blocks), dim3(256), 0, stream,
                     x, We, be, w1, w2, w3, Wh, bh, out, B);
}